// Round 8
// baseline (313.105 us; speedup 1.0000x reference)
//
#include <hip/hip_runtime.h>
#include <hip/hip_fp16.h>

// GeometryOptimalTransport: B=4, N=M=4096, C=128
// Sinkhorn (3 iters) over log_K(m,n) = -dist2/eps masked to -1e9, then
// attn-weighted gather of source feats.
//
// R2: validity iteration-invariant; finite NEG_INF=-1e9 contamination is
// closed-form: empty rows -> u=+1e9 EXACTLY; they add exp(0) to every column
// lse (per-batch count cc); all other invalid entries underflow to 0 in fp32.
// R5: 10x10 CSR spatial bins.
// R6: cooperative fusion FAILED (grid.sync cache flush, 7x).
// R8: the sweep kernel's ~106us was invariant to 4 structurally different
// inner loops (VALU issue only ~9us) -> stop materializing neighbor lists.
// lse/output consume the CSR bins DIRECTLY via the 12-slot MLP window scan.
// ecnt comes from lse_row iteration 0. feats converted to fp16 once (halves
// gather bytes; per-XCD L2-resident). 8 dispatches total.

constexpr int   BB = 4;
constexpr int   NN = 4096;
constexpr int   MM = 4096;
constexpr int   CC = 128;
constexpr int   LCAP = 512;                         // LDS compact cap (max ~330)
constexpr int   NSLOT = 12;                         // 768 candidate slots
constexpr int   G = 10, CSTRIDE = 104;              // 10x10 cells, padded CSR row
constexpr float kNegInf    = -1000000000.0f;
constexpr float kThresh2   = 0.04f;                 // 0.2^2
constexpr float kNegInvEps = -(1.0f / 0.01000001f); // -(1/(EPSILON+1e-8))

__device__ inline float wave_reduce_max(float x) {
#pragma unroll
  for (int off = 32; off > 0; off >>= 1)
    x = fmaxf(x, __shfl_xor(x, off, 64));
  return x;
}
__device__ inline float wave_reduce_sum(float x) {
#pragma unroll
  for (int off = 32; off > 0; off >>= 1)
    x += __shfl_xor(x, off, 64);
  return x;
}
__device__ inline int lane_prefix(unsigned long long m) {
  return __builtin_amdgcn_mbcnt_hi((unsigned)(m >> 32),
         __builtin_amdgcn_mbcnt_lo((unsigned)m, 0));
}

// 5x5-cell window over a CSR grid -> <=5 contiguous segments; slot j covers
// candidates q = 64j+lane mapped to segments via cndmask chain.
struct Window { int s0[5]; int Lc[6]; int T; };
__device__ inline Window make_window(const int* __restrict__ bs, float2 a) {
  Window w;
  int cx = min(max((int)(a.x * 10.0f), 0), 9);
  int cy = min(max((int)(a.y * 10.0f), 0), 9);
  int cy0 = max(cy - 2, 0), cy1 = min(cy + 2, 9);
  int cx0 = max(cx - 2, 0), cx1 = min(cx + 2, 9);
  int nseg = cy1 - cy0 + 1;
  w.Lc[0] = 0;
#pragma unroll
  for (int k = 0; k < 5; ++k) {
    int yy = min(cy0 + k, 9);
    bool act = k < nseg;
    int i0 = bs[yy * G + cx0];
    int i1 = bs[yy * G + cx1 + 1];
    w.s0[k] = i0;
    w.Lc[k + 1] = w.Lc[k] + (act ? (i1 - i0) : 0);
  }
  w.T = w.Lc[5] > NSLOT * 64 ? NSLOT * 64 : w.Lc[5];
  return w;
}
__device__ inline int slot_pos(const Window& w, int q, bool& act) {
  int adj = w.s0[0];
#pragma unroll
  for (int k = 1; k < 5; ++k)
    adj = (q >= w.Lc[k]) ? (w.s0[k] - w.Lc[k]) : adj;
  act = q < w.T;
  return act ? (q + adj) : 0;
}

// ---------------------------------------------------------------------------
// FAST PATH (~4.7 MB workspace)
// ---------------------------------------------------------------------------

// blocks 0..63: mask-fold locs (sentinels 1e9/3e9), zero v/ecnt.
// blocks 64..71: build per-(side,batch) 10x10 CSR bins of VALID points.
// blocks 72..1095: convert feats fp32 -> fp16 (packed half2 x4 per uint4).
__global__ __launch_bounds__(256) void prep_kernel(
    const float* __restrict__ sloc, const float* __restrict__ tloc,
    const int* __restrict__ sm, const int* __restrict__ tm,
    const float* __restrict__ feats,
    float* __restrict__ v, int* __restrict__ ecnt,
    float2* __restrict__ slm, float2* __restrict__ tlm,
    int* __restrict__ bin_start, float2* __restrict__ bin_loc,
    unsigned short* __restrict__ bin_pid, uint4* __restrict__ feats16)
{
  const int blk = blockIdx.x;
  const int tid = threadIdx.x;

  if (blk < 64) {
    int i = blk * 256 + tid;            // < 16384
    v[i] = 0.0f;
    float2 s = ((const float2*)sloc)[i];
    slm[i] = sm[i] ? s : make_float2(1.0e9f, 1.0e9f);
    float2 t = ((const float2*)tloc)[i];
    tlm[i] = tm[i] ? t : make_float2(3.0e9f, 3.0e9f);
    if (i < BB) ecnt[i] = 0;
    return;
  }
  if (blk >= 72) {
    // 2,097,152 floats = 524288 float4; 1024 blocks x 256 threads x 2 float4
    int i = (blk - 72) * 512 + tid * 2;
    const float4* __restrict__ f4 = (const float4*)feats;
    float4 x = f4[i], y = f4[i + 1];
    union { __half2 h[4]; uint4 u; } pk;
    pk.h[0] = __floats2half2_rn(x.x, x.y);
    pk.h[1] = __floats2half2_rn(x.z, x.w);
    pk.h[2] = __floats2half2_rn(y.x, y.y);
    pk.h[3] = __floats2half2_rn(y.z, y.w);
    feats16[i >> 1] = pk.u;
    return;
  }

  __shared__ int s_cnt[128];
  __shared__ int s_base[128];
  const int bb   = blk - 64;
  const int side = bb >> 2;              // 0 = sources, 1 = targets
  const int b    = bb & 3;
  const float2* __restrict__ loc =
      (const float2*)(side == 0 ? sloc : tloc) + (size_t)b * 4096;
  const int* __restrict__ msk = (side == 0 ? sm : tm) + (size_t)b * 4096;
  int* __restrict__ bsw = bin_start + (size_t)bb * CSTRIDE;
  float2* __restrict__ bloc = bin_loc + (size_t)bb * 4096;
  unsigned short* __restrict__ bpid = bin_pid + (size_t)bb * 4096;

  if (tid < 128) s_cnt[tid] = 0;
  __syncthreads();
  for (int i = tid; i < 4096; i += 256) {
    if (msk[i]) {
      float2 p = loc[i];
      int cx = min(max((int)(p.x * 10.0f), 0), 9);
      int cy = min(max((int)(p.y * 10.0f), 0), 9);
      atomicAdd(&s_cnt[cy * G + cx], 1);
    }
  }
  __syncthreads();
  if (tid < 64) {
    int x0 = s_cnt[tid], x1 = s_cnt[64 + tid];
    int s0 = x0;
#pragma unroll
    for (int off = 1; off < 64; off <<= 1) {
      int y = __shfl_up(s0, off, 64);
      if (tid >= off) s0 += y;
    }
    int tot0 = __shfl(s0, 63, 64);
    int s1 = x1;
#pragma unroll
    for (int off = 1; off < 64; off <<= 1) {
      int y = __shfl_up(s1, off, 64);
      if (tid >= off) s1 += y;
    }
    s1 += tot0;
    s_base[tid] = s0 - x0;               // exclusive starts, cells 0..63
    s_base[64 + tid] = s1 - x1;          // cells 64..127 (>=100 all = total)
    bsw[tid] = s0 - x0;
    if (64 + tid < CSTRIDE) bsw[64 + tid] = s1 - x1;
  }
  __syncthreads();
  for (int i = tid; i < 4096; i += 256) {
    if (msk[i]) {
      float2 p = loc[i];
      int cx = min(max((int)(p.x * 10.0f), 0), 9);
      int cy = min(max((int)(p.y * 10.0f), 0), 9);
      int pos = atomicAdd(&s_base[cy * G + cx], 1);
      bloc[pos] = p;
      bpid[pos] = (unsigned short)i;
    }
  }
}

// u[row] = -lse over valid in-radius sources (from bins), or +1e9 if none.
// iter==0 additionally counts empty rows into ecnt[b].
// grid 1024 blocks x 4 waves x 4 rows.
__global__ __launch_bounds__(256) void lse_row_bins_kernel(
    const float2* __restrict__ tlm,
    const int* __restrict__ bin_start, const float2* __restrict__ bin_loc,
    const unsigned short* __restrict__ bin_pid,
    const float* __restrict__ v, float* __restrict__ u,
    int* __restrict__ ecnt, int iter)
{
  const int lane = threadIdx.x & 63;
  const int wid  = threadIdx.x >> 6;
#pragma unroll
  for (int k = 0; k < 4; ++k) {
    const int row = blockIdx.x * 16 + wid * 4 + k;
    const int b   = row >> 12;
    const float2 a = tlm[row];
    const int* __restrict__ bs = bin_start + (size_t)b * CSTRIDE;  // source bins
    const float2* __restrict__ bl = bin_loc + (size_t)b * 4096;
    const unsigned short* __restrict__ bp = bin_pid + (size_t)b * 4096;
    const float* __restrict__ vb = v + (size_t)b * NN;

    float t[NSLOT];
    float mx = -3.0e38f;
    if (a.x < 1.5f) {
      Window w = make_window(bs, a);
#pragma unroll
      for (int j = 0; j < NSLOT; ++j) {
        bool act;
        int posc = slot_pos(w, j * 64 + lane, act);
        float2 s = bl[posc];
        int pid = bp[posc];
        float vv = vb[pid];
        float dx = a.x - s.x, dy = a.y - s.y;
        float d2 = dx * dx + dy * dy;
        bool val = act && (d2 < kThresh2);
        t[j] = val ? (d2 * kNegInvEps + vv) : -3.0e38f;
        mx = fmaxf(mx, t[j]);
      }
    } else {
#pragma unroll
      for (int j = 0; j < NSLOT; ++j) t[j] = -3.0e38f;
    }
    mx = wave_reduce_max(mx);
    if (mx < -1.0e37f) {                 // no valid in-radius entry
      if (lane == 0) {
        u[row] = 1.0e9f;
        if (iter == 0) atomicAdd(&ecnt[b], 1);
      }
      continue;
    }
    float ssum = 0.0f;
#pragma unroll
    for (int j = 0; j < NSLOT; ++j) ssum += __expf(t[j] - mx);
    ssum = wave_reduce_sum(ssum);
    if (lane == 0) u[row] = -(mx + __logf(ssum));
  }
}

// v[col] = 0 if source invalid; else -lse(valid terms + cc copies of t=0).
__global__ __launch_bounds__(256) void lse_col_bins_kernel(
    const float2* __restrict__ slm,
    const int* __restrict__ bin_start, const float2* __restrict__ bin_loc,
    const unsigned short* __restrict__ bin_pid,
    const int* __restrict__ ecnt,
    const float* __restrict__ u, float* __restrict__ v)
{
  const int lane = threadIdx.x & 63;
  const int wid  = threadIdx.x >> 6;
#pragma unroll
  for (int k = 0; k < 4; ++k) {
    const int col = blockIdx.x * 16 + wid * 4 + k;
    const int b   = col >> 12;
    const float2 a = slm[col];
    if (a.x > 1.5f) { if (lane == 0) v[col] = 0.0f; continue; }
    const int* __restrict__ bs = bin_start + (size_t)(4 + b) * CSTRIDE; // target bins
    const float2* __restrict__ bl = bin_loc + (size_t)(4 + b) * 4096;
    const unsigned short* __restrict__ bp = bin_pid + (size_t)(4 + b) * 4096;
    const float* __restrict__ ub = u + (size_t)b * MM;

    float t[NSLOT];
    float mx = -3.0e38f;
    Window w = make_window(bs, a);
#pragma unroll
    for (int j = 0; j < NSLOT; ++j) {
      bool act;
      int posc = slot_pos(w, j * 64 + lane, act);
      float2 s = bl[posc];
      int pid = bp[posc];
      float uu = ub[pid];
      float dx = a.x - s.x, dy = a.y - s.y;
      float d2 = dx * dx + dy * dy;
      bool val = act && (d2 < kThresh2);
      t[j] = val ? (d2 * kNegInvEps + uu) : -3.0e38f;
      mx = fmaxf(mx, t[j]);
    }
    mx = wave_reduce_max(mx);
    const int cc = ecnt[b];
    if (cc > 0) mx = fmaxf(mx, 0.0f);    // contamination entries are t = 0.0
    if (mx < -1.0e37f) { if (lane == 0) v[col] = 1.0e9f; continue; }
    float ssum = 0.0f;
#pragma unroll
    for (int j = 0; j < NSLOT; ++j) ssum += __expf(t[j] - mx);
    ssum = wave_reduce_sum(ssum);
    if (lane == 0)
      v[col] = -(mx + __logf(ssum + (float)cc * __expf(0.0f - mx)));
  }
}

// out[row,:] = sum attn * feats16[n,:]. grid 4096 blocks x 4 rows. Per row:
// 4 waves scan 3 slots each, compact (pid,d2) into LDS via shared atomic;
// attn phase; gather fp16 rows 16 lanes x 16B with 16 entries in flight.
__global__ __launch_bounds__(256) void output_bins_kernel(
    const float2* __restrict__ tlm,
    const int* __restrict__ bin_start, const float2* __restrict__ bin_loc,
    const unsigned short* __restrict__ bin_pid,
    const float* __restrict__ u, const float* __restrict__ v,
    const uint4* __restrict__ feats16, float* __restrict__ out)
{
  __shared__ unsigned short s_pid[LCAP];
  __shared__ float s_val[LCAP];
  __shared__ int s_cnt;
  __shared__ float4 s_red[256][2];

  const int tid  = threadIdx.x;
  const int lane = tid & 63;
  const int wid  = tid >> 6;

  for (int k = 0; k < 4; ++k) {
    const int row = blockIdx.x * 4 + k;
    const int b   = row >> 12;
    if (tid == 0) s_cnt = 0;
    __syncthreads();

    const float2 a = tlm[row];
    if (a.x < 1.5f) {
      const int* __restrict__ bs = bin_start + (size_t)b * CSTRIDE;
      const float2* __restrict__ bl = bin_loc + (size_t)b * 4096;
      const unsigned short* __restrict__ bp = bin_pid + (size_t)b * 4096;
      Window w = make_window(bs, a);
#pragma unroll
      for (int jj = 0; jj < 3; ++jj) {   // wave wid owns slots 3*wid..3*wid+2
        int j = wid * 3 + jj;
        bool act;
        int posc = slot_pos(w, j * 64 + lane, act);
        float2 s = bl[posc];
        int pid = bp[posc];
        float dx = a.x - s.x, dy = a.y - s.y;
        float d2 = dx * dx + dy * dy;
        bool val = act && (d2 < kThresh2);
        unsigned long long mm = __ballot(val);
        int base = 0;
        if (lane == 0) base = atomicAdd(&s_cnt, __popcll(mm));
        base = __shfl(base, 0, 64);
        if (val) {
          int off = base + lane_prefix(mm);
          if (off < LCAP) { s_pid[off] = (unsigned short)pid; s_val[off] = d2; }
        }
      }
    }
    __syncthreads();
    int cnt = s_cnt;
    if (cnt > LCAP) cnt = LCAP;
    float4* op = (float4*)(out + (size_t)row * CC);
    if (cnt == 0) {                      // !tgt_valid or !has_source
      if (tid < 32) op[tid] = make_float4(0.f, 0.f, 0.f, 0.f);
      __syncthreads();
      continue;
    }
    const float um = u[row];
    const float* __restrict__ vb = v + (size_t)b * NN;
    for (int j = tid; j < cnt; j += 256)
      s_val[j] = __expf(s_val[j] * kNegInvEps + um + vb[s_pid[j]]);
    __syncthreads();

    const int g = tid >> 4, l = tid & 15;           // 16 groups x 16 lanes
    const uint4* __restrict__ fb = feats16 + (size_t)b * 4096 * 16;
    float4 accA = make_float4(0.f, 0.f, 0.f, 0.f);
    float4 accB = make_float4(0.f, 0.f, 0.f, 0.f);
    for (int j = g; j < cnt; j += 16) {
      float aw = s_val[j];
      int   n  = s_pid[j];
      union { uint4 u; __half2 h[4]; } q;
      q.u = fb[(size_t)n * 16 + l];
      float2 p0 = __half22float2(q.h[0]);
      float2 p1 = __half22float2(q.h[1]);
      float2 p2 = __half22float2(q.h[2]);
      float2 p3 = __half22float2(q.h[3]);
      accA.x = fmaf(aw, p0.x, accA.x); accA.y = fmaf(aw, p0.y, accA.y);
      accA.z = fmaf(aw, p1.x, accA.z); accA.w = fmaf(aw, p1.y, accA.w);
      accB.x = fmaf(aw, p2.x, accB.x); accB.y = fmaf(aw, p2.y, accB.y);
      accB.z = fmaf(aw, p3.x, accB.z); accB.w = fmaf(aw, p3.y, accB.w);
    }
    s_red[tid][0] = accA;
    s_red[tid][1] = accB;
    __syncthreads();
    if (tid < 16) {
      float4 r0 = s_red[tid][0], r1 = s_red[tid][1];
#pragma unroll
      for (int gg = 1; gg < 16; ++gg) {
        float4 p0 = s_red[gg * 16 + tid][0], p1 = s_red[gg * 16 + tid][1];
        r0.x += p0.x; r0.y += p0.y; r0.z += p0.z; r0.w += p0.w;
        r1.x += p1.x; r1.y += p1.y; r1.z += p1.z; r1.w += p1.w;
      }
      op[2 * tid] = r0;
      op[2 * tid + 1] = r1;
    }
    __syncthreads();
  }
}

// ---------------------------------------------------------------------------
// FALLBACK: round-1 dense path (~128 KB workspace)
// ---------------------------------------------------------------------------

__global__ __launch_bounds__(256) void init_v_kernel(float* __restrict__ v) {
  int i = blockIdx.x * 256 + threadIdx.x;
  if (i < BB * NN) v[i] = 0.0f;
}

__global__ __launch_bounds__(256) void u_update_kernel(
    const float* __restrict__ src_locs, const float* __restrict__ tgt_locs,
    const int* __restrict__ src_valid, const int* __restrict__ tgt_valid,
    const float* __restrict__ v, float* __restrict__ u)
{
  const int lane = threadIdx.x & 63;
  const int row  = blockIdx.x * 4 + (threadIdx.x >> 6);
  const int b    = row / MM;
  const float tx = tgt_locs[row * 2 + 0];
  const float ty = tgt_locs[row * 2 + 1];
  const bool  tv = tgt_valid[row] != 0;
  const float2* __restrict__ sl  = (const float2*)(src_locs + (size_t)b * NN * 2);
  const float*  __restrict__ vb  = v + (size_t)b * NN;
  const int*    __restrict__ svb = src_valid + (size_t)b * NN;
  float mx = -3.0e38f;
#pragma unroll 4
  for (int i = 0; i < NN / 64; ++i) {
    int n = i * 64 + lane;
    float2 s = sl[n];
    float dx = tx - s.x, dy = ty - s.y;
    float d2 = dx * dx + dy * dy;
    bool valid = (d2 < kThresh2) & tv & (svb[n] != 0);
    float t = (valid ? d2 * kNegInvEps : kNegInf) + vb[n];
    mx = fmaxf(mx, t);
  }
  mx = wave_reduce_max(mx);
  float s = 0.0f;
#pragma unroll 4
  for (int i = 0; i < NN / 64; ++i) {
    int n = i * 64 + lane;
    float2 sc = sl[n];
    float dx = tx - sc.x, dy = ty - sc.y;
    float d2 = dx * dx + dy * dy;
    bool valid = (d2 < kThresh2) & tv & (svb[n] != 0);
    float t = (valid ? d2 * kNegInvEps : kNegInf) + vb[n];
    s += __expf(t - mx);
  }
  s = wave_reduce_sum(s);
  if (lane == 0) u[row] = -(mx + __logf(s));
}

__global__ __launch_bounds__(256) void v_update_kernel(
    const float* __restrict__ src_locs, const float* __restrict__ tgt_locs,
    const int* __restrict__ src_valid, const int* __restrict__ tgt_valid,
    const float* __restrict__ u, float* __restrict__ v)
{
  const int lane = threadIdx.x & 63;
  const int col  = blockIdx.x * 4 + (threadIdx.x >> 6);
  const int b    = col / NN;
  const float sx = src_locs[col * 2 + 0];
  const float sy = src_locs[col * 2 + 1];
  const bool  sv = src_valid[col] != 0;
  const float2* __restrict__ tl  = (const float2*)(tgt_locs + (size_t)b * MM * 2);
  const float*  __restrict__ ub  = u + (size_t)b * MM;
  const int*    __restrict__ tvb = tgt_valid + (size_t)b * MM;
  float mx = -3.0e38f;
#pragma unroll 4
  for (int i = 0; i < MM / 64; ++i) {
    int m = i * 64 + lane;
    float2 t2 = tl[m];
    float dx = t2.x - sx, dy = t2.y - sy;
    float d2 = dx * dx + dy * dy;
    bool valid = (d2 < kThresh2) & sv & (tvb[m] != 0);
    float t = (valid ? d2 * kNegInvEps : kNegInf) + ub[m];
    mx = fmaxf(mx, t);
  }
  mx = wave_reduce_max(mx);
  float s = 0.0f;
#pragma unroll 4
  for (int i = 0; i < MM / 64; ++i) {
    int m = i * 64 + lane;
    float2 t2 = tl[m];
    float dx = t2.x - sx, dy = t2.y - sy;
    float d2 = dx * dx + dy * dy;
    bool valid = (d2 < kThresh2) & sv & (tvb[m] != 0);
    float t = (valid ? d2 * kNegInvEps : kNegInf) + ub[m];
    s += __expf(t - mx);
  }
  s = wave_reduce_sum(s);
  if (lane == 0) v[col] = sv ? -(mx + __logf(s)) : 0.0f;
}

__global__ __launch_bounds__(256) void output_kernel(
    const float* __restrict__ src_locs, const float* __restrict__ tgt_locs,
    const int* __restrict__ src_valid, const int* __restrict__ tgt_valid,
    const float* __restrict__ u, const float* __restrict__ v,
    const float* __restrict__ feats, float* __restrict__ out)
{
  __shared__ float s_attn[NN];
  __shared__ int   s_idx[NN];
  __shared__ int   s_cnt;
  __shared__ float s_part[CC];
  const int row = blockIdx.x;
  const int b   = row / MM;
  const int tid = threadIdx.x;
  if (tid == 0) s_cnt = 0;
  __syncthreads();
  const float tx = tgt_locs[row * 2 + 0];
  const float ty = tgt_locs[row * 2 + 1];
  const bool  tv = tgt_valid[row] != 0;
  const float um = u[row];
  const float2* __restrict__ sl  = (const float2*)(src_locs + (size_t)b * NN * 2);
  const float*  __restrict__ vb  = v + (size_t)b * NN;
  const int*    __restrict__ svb = src_valid + (size_t)b * NN;
#pragma unroll 4
  for (int i = 0; i < NN / 256; ++i) {
    int n = i * 256 + tid;
    float2 s = sl[n];
    float dx = tx - s.x, dy = ty - s.y;
    float d2 = dx * dx + dy * dy;
    bool valid = (d2 < kThresh2) & tv & (svb[n] != 0);
    if (valid) {
      float a = __expf((d2 * kNegInvEps + um) + vb[n]);
      int p = atomicAdd(&s_cnt, 1);
      s_attn[p] = a;
      s_idx[p]  = n;
    }
  }
  __syncthreads();
  const int cnt = s_cnt;
  const int g = tid >> 7;
  const int c = tid & (CC - 1);
  const float* __restrict__ fb = feats + (size_t)b * NN * CC;
  float acc = 0.0f;
  for (int j = g; j < cnt; j += 2) {
    float a = s_attn[j];
    int   n = s_idx[j];
    acc = fmaf(a, fb[(size_t)n * CC + c], acc);
  }
  if (g == 1) s_part[c] = acc;
  __syncthreads();
  if (g == 0) {
    float r = (cnt > 0) ? (acc + s_part[c]) : 0.0f;
    out[(size_t)row * CC + c] = r;
  }
}

// ---------------------------------------------------------------------------

extern "C" void kernel_launch(void* const* d_in, const int* in_sizes, int n_in,
                              void* d_out, int out_size, void* d_ws, size_t ws_size,
                              hipStream_t stream) {
  const float* feats = (const float*)d_in[0];
  const float* sloc  = (const float*)d_in[1];
  const float* tloc  = (const float*)d_in[2];
  const int*   smask = (const int*)d_in[3];
  const int*   tmask = (const int*)d_in[4];
  float* out = (float*)d_out;

  // workspace layout (fast path, ~4.7 MB)
  char* p = (char*)d_ws;
  float* u_   = (float*)p;            p += (size_t)BB * MM * 4;
  float* v_   = (float*)p;            p += (size_t)BB * NN * 4;
  int* ecnt   = (int*)p;              p += 256;
  float2* slm = (float2*)p;           p += (size_t)BB * NN * 8;
  float2* tlm = (float2*)p;           p += (size_t)BB * MM * 8;
  int* bin_start = (int*)p;           p += (size_t)8 * CSTRIDE * 4;
  float2* bin_loc = (float2*)p;       p += (size_t)8 * 4096 * 8;
  unsigned short* bin_pid = (unsigned short*)p; p += (size_t)8 * 4096 * 2;
  uint4* feats16 = (uint4*)p;         p += (size_t)BB * NN * CC * 2;
  size_t required = (size_t)(p - (char*)d_ws);

  if (ws_size >= required) {
    prep_kernel<<<1096, 256, 0, stream>>>(
        sloc, tloc, smask, tmask, feats, v_, ecnt, slm, tlm,
        bin_start, bin_loc, bin_pid, feats16);
    for (int it = 0; it < 3; ++it) {
      lse_row_bins_kernel<<<1024, 256, 0, stream>>>(
          tlm, bin_start, bin_loc, bin_pid, v_, u_, ecnt, it);
      lse_col_bins_kernel<<<1024, 256, 0, stream>>>(
          slm, bin_start, bin_loc, bin_pid, ecnt, u_, v_);
    }
    output_bins_kernel<<<4096, 256, 0, stream>>>(
        tlm, bin_start, bin_loc, bin_pid, u_, v_, feats16, out);
  } else {
    // minimal-workspace fallback: round-1 dense path
    float* u = (float*)d_ws;
    float* v = u + (size_t)BB * MM;
    init_v_kernel<<<(BB * NN + 255) / 256, 256, 0, stream>>>(v);
    for (int it = 0; it < 3; ++it) {
      u_update_kernel<<<BB * MM / 4, 256, 0, stream>>>(sloc, tloc, smask, tmask, v, u);
      v_update_kernel<<<BB * NN / 4, 256, 0, stream>>>(sloc, tloc, smask, tmask, u, v);
    }
    output_kernel<<<BB * MM, 256, 0, stream>>>(sloc, tloc, smask, tmask, u, v, feats, out);
  }
}